// Round 6
// baseline (1106.493 us; speedup 1.0000x reference)
//
#include <hip/hip_runtime.h>
#include <math.h>

#define NN 100000
#define NE 1600000
#define NG 64
#define CC 64
#define KK 128
#define EPSI 1e-5f

// ---- workspace layout (float offsets) ----
#define WS_H      0          // h[NN*64]  25.6 MB
#define WS_P      6400000    // p[NN*8]   head projections (dead after k_alpha)
#define WS_CNT    7200000    // int cnt[NN]
#define WS_OFF    7300000    // int off[NN+1]
#define WS_CUR    7500000    // int cursor[NN]
#define WS_DEG    7600000    // deg[NN]
#define WS_DINV   7700000    // dinv[NN]
#define WS_MEAN   7800000
#define WS_RINV   7804096
#define WS_START  7808192
#define WS_CSR    7900000    // int2 csr[NE]  (col, w bits)  12.8 MB

// ---- output layout (float offsets) ----
#define OUT_ALPHA 6400000
#define OUT_IDX   8000000

// h = x @ W, wave-per-row, W staged in LDS
__global__ __launch_bounds__(256) void k_gemm(const float* __restrict__ x,
                                              const float* __restrict__ w,
                                              float* __restrict__ h) {
    __shared__ float wl[KK * CC];
    for (int i = threadIdx.x; i < KK * CC; i += 256) wl[i] = w[i];
    __syncthreads();
    int lane = threadIdx.x & 63;
    int wid  = (blockIdx.x * 256 + threadIdx.x) >> 6;
    int nw   = (gridDim.x * 256) >> 6;
    for (int row = wid; row < NN; row += nw) {
        const float* xr = x + (size_t)row * KK;
        float acc = 0.f;
        #pragma unroll
        for (int k = 0; k < KK; k += 4) {
            float4 xv = *reinterpret_cast<const float4*>(xr + k);
            acc += xv.x * wl[(k + 0) * CC + lane];
            acc += xv.y * wl[(k + 1) * CC + lane];
            acc += xv.z * wl[(k + 2) * CC + lane];
            acc += xv.w * wl[(k + 3) * CC + lane];
        }
        h[(size_t)row * CC + lane] = acc;
    }
}

__global__ void k_starts(const int* __restrict__ bm, int* __restrict__ start) {
    int i = blockIdx.x * blockDim.x + threadIdx.x;
    if (i > NN) return;
    if (i == 0) {
        int b = bm[0];
        for (int g = 0; g <= b; ++g) start[g] = 0;
    } else if (i == NN) {
        int b = bm[NN - 1];
        for (int g = b + 1; g <= NG; ++g) start[g] = NN;
    } else {
        int b0 = bm[i - 1], b1 = bm[i];
        for (int g = b0 + 1; g <= b1; ++g) start[g] = i;
    }
}

__global__ __launch_bounds__(256) void k_stats(const float* __restrict__ h,
                                               const int* __restrict__ start,
                                               float* __restrict__ meanb,
                                               float* __restrict__ rinvb) {
    __shared__ float ssum[4][64], ssq[4][64];
    int g = blockIdx.x;
    int s = start[g], e = start[g + 1];
    int w = threadIdx.x >> 6, lane = threadIdx.x & 63;
    float a = 0.f, b = 0.f;
    for (int r = s + w; r < e; r += 4) {
        float v = h[(size_t)r * CC + lane];
        a += v; b += v * v;
    }
    ssum[w][lane] = a; ssq[w][lane] = b;
    __syncthreads();
    if (w == 0) {
        a = ssum[0][lane] + ssum[1][lane] + ssum[2][lane] + ssum[3][lane];
        b = ssq[0][lane] + ssq[1][lane] + ssq[2][lane] + ssq[3][lane];
        float mean = 0.f, rinv = 0.f;
        if (e > s) {
            float cnt = (float)(e - s);
            mean = a / cnt;
            float var = b / cnt - mean * mean;
            rinv = rsqrtf(var + EPSI);
        }
        meanb[g * 64 + lane] = mean;
        rinvb[g * 64 + lane] = rinv;
    }
}

__global__ void k_norm(float* __restrict__ h, const int* __restrict__ bm,
                       const float* __restrict__ meanb, const float* __restrict__ rinvb) {
    int id = blockIdx.x * blockDim.x + threadIdx.x;
    if (id >= NN * 16) return;
    int i = id >> 4, c4 = (id & 15) << 2;
    int g = bm[i];
    float4 v = *reinterpret_cast<float4*>(h + (size_t)i * CC + c4);
    float4 m = *reinterpret_cast<const float4*>(meanb + g * 64 + c4);
    float4 r = *reinterpret_cast<const float4*>(rinvb + g * 64 + c4);
    v.x = (v.x - m.x) * r.x;
    v.y = (v.y - m.y) * r.y;
    v.z = (v.z - m.z) * r.z;
    v.w = (v.w - m.w) * r.w;
    *reinterpret_cast<float4*>(h + (size_t)i * CC + c4) = v;
}

__global__ __launch_bounds__(256) void k_proj(const float* __restrict__ h,
                                              const float* __restrict__ aw,
                                              float* __restrict__ p) {
    __shared__ float awl[4 * KK];
    for (int i = threadIdx.x; i < 4 * KK; i += 256) awl[i] = aw[i];
    __syncthreads();
    int id = blockIdx.x * 256 + threadIdx.x;
    int n = id >> 3, j = id & 7;
    if (n >= NN) return;
    int hd = j & 3, half = (j >> 2) * 64;
    const float* hr = h + (size_t)n * CC;
    float acc = 0.f;
    #pragma unroll
    for (int c = 0; c < CC; c += 4) {
        float4 v = *reinterpret_cast<const float4*>(hr + c);
        acc += v.x * awl[hd * KK + half + c + 0];
        acc += v.y * awl[hd * KK + half + c + 1];
        acc += v.z * awl[hd * KK + half + c + 2];
        acc += v.w * awl[hd * KK + half + c + 3];
    }
    p[(size_t)n * 8 + j] = acc;
}

__global__ __launch_bounds__(256) void k_alpha(const float* __restrict__ p,
                                               const int* __restrict__ ei,
                                               const float* __restrict__ ab,
                                               const float* __restrict__ ea,
                                               float* __restrict__ alpha_out,
                                               float* __restrict__ deg) {
    int e = blockIdx.x * 256 + threadIdx.x;
    if (e >= NE) return;
    int row = ei[e], col = ei[NE + e];
    float a;
    if (row == col) {
        a = 1.f;
    } else {
        float4 pr = *reinterpret_cast<const float4*>(p + (size_t)row * 8);
        float4 pc = *reinterpret_cast<const float4*>(p + (size_t)col * 8 + 4);
        float4 bb = *reinterpret_cast<const float4*>(ab);
        float ev = ea[e];
        float s0 = ev / (1.f + __expf(-(pr.x + pc.x + bb.x)));
        float s1 = ev / (1.f + __expf(-(pr.y + pc.y + bb.y)));
        float s2 = ev / (1.f + __expf(-(pr.z + pc.z + bb.z)));
        float s3 = ev / (1.f + __expf(-(pr.w + pc.w + bb.w)));
        a = 0.25f * (s0 + s1 + s2 + s3);
    }
    alpha_out[e] = a;
    atomicAdd(deg + row, fabsf(a));
}

__global__ void k_dinv(const float* __restrict__ deg, float* __restrict__ dinv) {
    int n = blockIdx.x * blockDim.x + threadIdx.x;
    if (n >= NN) return;
    float d = deg[n];
    dinv[n] = (d > 0.f) ? rsqrtf(d) : 0.f;
}

// ---- CSR build: histogram -> scan -> place ----
__global__ void k_count(const int* __restrict__ ei, int* __restrict__ cnt) {
    int e = blockIdx.x * blockDim.x + threadIdx.x;
    if (e >= NE) return;
    atomicAdd(cnt + ei[e], 1);
}

__global__ __launch_bounds__(1024) void k_scan(const int* __restrict__ cnt,
                                               int* __restrict__ off,
                                               int* __restrict__ cursor) {
    __shared__ int part[1024];
    int t = threadIdx.x;
    const int CH = (NN + 1023) / 1024;  // 98
    int s = t * CH, e = s + CH; if (e > NN) e = NN; if (s > NN) s = NN;
    int sum = 0;
    for (int i = s; i < e; ++i) sum += cnt[i];
    part[t] = sum;
    __syncthreads();
    for (int o = 1; o < 1024; o <<= 1) {
        int v = (t >= o) ? part[t - o] : 0;
        __syncthreads();
        part[t] += v;
        __syncthreads();
    }
    int base = (t == 0) ? 0 : part[t - 1];
    for (int i = s; i < e; ++i) { off[i] = base; cursor[i] = base; base += cnt[i]; }
    if (t == 1023) off[NN] = part[1023];
}

// place edge into its row bucket with precomputed weight alpha*dinv[col]
__global__ __launch_bounds__(256) void k_place(const int* __restrict__ ei,
                                               const float* __restrict__ alpha,
                                               const float* __restrict__ dinv,
                                               int* __restrict__ cursor,
                                               int2* __restrict__ csr) {
    int e = blockIdx.x * 256 + threadIdx.x;
    if (e >= NE) return;
    int row = ei[e], col = ei[NE + e];
    float w = alpha[e] * dinv[col];
    int slot = atomicAdd(cursor + row, 1);
    csr[slot] = make_int2(col, __float_as_int(w));
}

// wave-per-node gather: out[n] = dinv[n] * sum_e w_e * h[col_e]   (no atomics)
__global__ __launch_bounds__(256) void k_gather(const float* __restrict__ h,
                                                const int* __restrict__ off,
                                                const int2* __restrict__ csr,
                                                const float* __restrict__ dinv,
                                                float* __restrict__ out) {
    int lane = threadIdx.x & 63;
    int n = (blockIdx.x * 256 + threadIdx.x) >> 6;
    if (n >= NN) return;
    int s = off[n], e = off[n + 1];
    float acc = 0.f;
    for (int i = s; i < e; ++i) {
        int2 cw = csr[i];  // wave-uniform 8B
        acc += __int_as_float(cw.y) * h[(size_t)cw.x * CC + lane];
    }
    out[(size_t)n * CC + lane] = dinv[n] * acc;
}

__global__ void k_idx(const int* __restrict__ ei, float* __restrict__ o) {
    int i = blockIdx.x * blockDim.x + threadIdx.x;
    if (i >= 2 * NE) return;
    o[i] = (float)ei[i];
}

extern "C" void kernel_launch(void* const* d_in, const int* in_sizes, int n_in,
                              void* d_out, int out_size, void* d_ws, size_t ws_size,
                              hipStream_t stream) {
    const float* x  = (const float*)d_in[0];
    const float* w  = (const float*)d_in[1];
    const float* aw = (const float*)d_in[2];
    const float* ab = (const float*)d_in[3];
    const float* ea = (const float*)d_in[4];
    const int*   ei = (const int*)d_in[5];
    const int*   bm = (const int*)d_in[6];
    float* out = (float*)d_out;
    float* ws  = (float*)d_ws;
    float* h     = ws + WS_H;
    float* p     = ws + WS_P;
    int*   cnt   = (int*)(ws + WS_CNT);
    int*   off   = (int*)(ws + WS_OFF);
    int*   cur   = (int*)(ws + WS_CUR);
    float* deg   = ws + WS_DEG;
    float* dinv  = ws + WS_DINV;
    float* meanb = ws + WS_MEAN;
    float* rinvb = ws + WS_RINV;
    int*   start = (int*)(ws + WS_START);
    int2*  csr   = (int2*)(ws + WS_CSR);

    hipMemsetAsync(cnt, 0, (size_t)NN * 4, stream);
    hipMemsetAsync(deg, 0, (size_t)NN * 4, stream);

    k_gemm  <<<2500, 256, 0, stream>>>(x, w, h);
    k_starts<<<(NN + 256) / 256, 256, 0, stream>>>(bm, start);
    k_stats <<<NG, 256, 0, stream>>>(h, start, meanb, rinvb);
    k_norm  <<<(NN * 16 + 255) / 256, 256, 0, stream>>>(h, bm, meanb, rinvb);
    k_proj  <<<(NN * 8 + 255) / 256, 256, 0, stream>>>(h, aw, p);
    k_count <<<(NE + 255) / 256, 256, 0, stream>>>(ei, cnt);
    k_scan  <<<1, 1024, 0, stream>>>(cnt, off, cur);
    k_alpha <<<(NE + 255) / 256, 256, 0, stream>>>(p, ei, ab, ea, out + OUT_ALPHA, deg);
    k_dinv  <<<(NN + 255) / 256, 256, 0, stream>>>(deg, dinv);
    k_place <<<(NE + 255) / 256, 256, 0, stream>>>(ei, out + OUT_ALPHA, dinv, cur, csr);
    k_gather<<<25000, 256, 0, stream>>>(h, off, csr, dinv, out);
    k_idx   <<<(2 * NE + 255) / 256, 256, 0, stream>>>(ei, out + OUT_IDX);
}

// Round 7
// 944.336 us; speedup vs baseline: 1.1717x; 1.1717x over previous
//
#include <hip/hip_runtime.h>
#include <math.h>

#define NN 100000
#define NE 1600000
#define NG 64
#define CC 64
#define KK 128
#define EPSI 1e-5f
#define TR 64   // gemm row tile

// ---- workspace layout (float offsets) ----
#define WS_H      0          // h[NN*64]  25.6 MB
#define WS_P      6400000    // p[NN*8]   head projections (dead after k_alpha)
#define WS_CNT    7200000    // int cnt[NN]
#define WS_OFF    7300000    // int off[NN+1]
#define WS_CUR    7500000    // int cursor[NN]
#define WS_DEG    7600000    // deg[NN]
#define WS_DINV   7700000    // dinv[NN]
#define WS_MEAN   7800000
#define WS_RINV   7804096
#define WS_START  7808192
#define WS_CSR    7900000    // int2 csr[NE]  (col, w bits)  12.8 MB

// ---- output layout (float offsets) ----
#define OUT_ALPHA 6400000
#define OUT_IDX   8000000

// h = x @ W  — 64x64 tile/block, 4x4 register tile/thread, xT+W in LDS.
// xT padded to stride 68: x-read = 4 addrs x 4 words = 16 banks (conflict-free),
// w-read = 16 addrs x 4 words = 2-way (free, m136).
__global__ __launch_bounds__(256) void k_gemm(const float* __restrict__ x,
                                              const float* __restrict__ w,
                                              float* __restrict__ h) {
    __shared__ float xt[KK][TR + 4];   // 34816 B
    __shared__ float wl[KK * CC];      // 32768 B
    int tid = threadIdx.x;
    for (int i = tid; i < KK * CC; i += 256) wl[i] = w[i];
    int base = blockIdx.x * TR;
    int nrow = NN - base; if (nrow > TR) nrow = TR;
    for (int i = tid; i < TR * KK; i += 256) {
        int r = i >> 7, k = i & (KK - 1);          // consecutive tid -> consecutive k (coalesced)
        xt[k][r] = (r < nrow) ? x[(size_t)(base + r) * KK + k] : 0.f;
    }
    __syncthreads();
    int cgrp = tid & 15, rgrp = tid >> 4;          // 16x16 thread grid of 4x4 tiles
    int c0 = cgrp << 2, r0 = rgrp << 2;
    float acc[4][4];
    #pragma unroll
    for (int i = 0; i < 4; ++i)
        #pragma unroll
        for (int j = 0; j < 4; ++j) acc[i][j] = 0.f;
    #pragma unroll 8
    for (int k = 0; k < KK; ++k) {
        float4 xv = *reinterpret_cast<const float4*>(&xt[k][r0]);
        float4 wv = *reinterpret_cast<const float4*>(&wl[k * CC + c0]);
        acc[0][0] += xv.x * wv.x; acc[0][1] += xv.x * wv.y; acc[0][2] += xv.x * wv.z; acc[0][3] += xv.x * wv.w;
        acc[1][0] += xv.y * wv.x; acc[1][1] += xv.y * wv.y; acc[1][2] += xv.y * wv.z; acc[1][3] += xv.y * wv.w;
        acc[2][0] += xv.z * wv.x; acc[2][1] += xv.z * wv.y; acc[2][2] += xv.z * wv.z; acc[2][3] += xv.z * wv.w;
        acc[3][0] += xv.w * wv.x; acc[3][1] += xv.w * wv.y; acc[3][2] += xv.w * wv.z; acc[3][3] += xv.w * wv.w;
    }
    #pragma unroll
    for (int i = 0; i < 4; ++i) {
        if (r0 + i < nrow) {
            float4 o = make_float4(acc[i][0], acc[i][1], acc[i][2], acc[i][3]);
            *reinterpret_cast<float4*>(&h[(size_t)(base + r0 + i) * CC + c0]) = o;
        }
    }
}

__global__ void k_starts(const int* __restrict__ bm, int* __restrict__ start) {
    int i = blockIdx.x * blockDim.x + threadIdx.x;
    if (i > NN) return;
    if (i == 0) {
        int b = bm[0];
        for (int g = 0; g <= b; ++g) start[g] = 0;
    } else if (i == NN) {
        int b = bm[NN - 1];
        for (int g = b + 1; g <= NG; ++g) start[g] = NN;
    } else {
        int b0 = bm[i - 1], b1 = bm[i];
        for (int g = b0 + 1; g <= b1; ++g) start[g] = i;
    }
}

__global__ __launch_bounds__(256) void k_stats(const float* __restrict__ h,
                                               const int* __restrict__ start,
                                               float* __restrict__ meanb,
                                               float* __restrict__ rinvb) {
    __shared__ float ssum[4][64], ssq[4][64];
    int g = blockIdx.x;
    int s = start[g], e = start[g + 1];
    int w = threadIdx.x >> 6, lane = threadIdx.x & 63;
    float a = 0.f, b = 0.f;
    for (int r = s + w; r < e; r += 4) {
        float v = h[(size_t)r * CC + lane];
        a += v; b += v * v;
    }
    ssum[w][lane] = a; ssq[w][lane] = b;
    __syncthreads();
    if (w == 0) {
        a = ssum[0][lane] + ssum[1][lane] + ssum[2][lane] + ssum[3][lane];
        b = ssq[0][lane] + ssq[1][lane] + ssq[2][lane] + ssq[3][lane];
        float mean = 0.f, rinv = 0.f;
        if (e > s) {
            float cnt = (float)(e - s);
            mean = a / cnt;
            float var = b / cnt - mean * mean;
            rinv = rsqrtf(var + EPSI);
        }
        meanb[g * 64 + lane] = mean;
        rinvb[g * 64 + lane] = rinv;
    }
}

__global__ void k_norm(float* __restrict__ h, const int* __restrict__ bm,
                       const float* __restrict__ meanb, const float* __restrict__ rinvb) {
    int id = blockIdx.x * blockDim.x + threadIdx.x;
    if (id >= NN * 16) return;
    int i = id >> 4, c4 = (id & 15) << 2;
    int g = bm[i];
    float4 v = *reinterpret_cast<float4*>(h + (size_t)i * CC + c4);
    float4 m = *reinterpret_cast<const float4*>(meanb + g * 64 + c4);
    float4 r = *reinterpret_cast<const float4*>(rinvb + g * 64 + c4);
    v.x = (v.x - m.x) * r.x;
    v.y = (v.y - m.y) * r.y;
    v.z = (v.z - m.z) * r.z;
    v.w = (v.w - m.w) * r.w;
    *reinterpret_cast<float4*>(h + (size_t)i * CC + c4) = v;
}

__global__ __launch_bounds__(256) void k_proj(const float* __restrict__ h,
                                              const float* __restrict__ aw,
                                              float* __restrict__ p) {
    __shared__ float awl[4 * KK];
    for (int i = threadIdx.x; i < 4 * KK; i += 256) awl[i] = aw[i];
    __syncthreads();
    int id = blockIdx.x * 256 + threadIdx.x;
    int n = id >> 3, j = id & 7;
    if (n >= NN) return;
    int hd = j & 3, half = (j >> 2) * 64;
    const float* hr = h + (size_t)n * CC;
    float acc = 0.f;
    #pragma unroll
    for (int c = 0; c < CC; c += 4) {
        float4 v = *reinterpret_cast<const float4*>(hr + c);
        acc += v.x * awl[hd * KK + half + c + 0];
        acc += v.y * awl[hd * KK + half + c + 1];
        acc += v.z * awl[hd * KK + half + c + 2];
        acc += v.w * awl[hd * KK + half + c + 3];
    }
    p[(size_t)n * 8 + j] = acc;
}

__global__ __launch_bounds__(256) void k_alpha(const float* __restrict__ p,
                                               const int* __restrict__ ei,
                                               const float* __restrict__ ab,
                                               const float* __restrict__ ea,
                                               float* __restrict__ alpha_out,
                                               float* __restrict__ deg) {
    int e = blockIdx.x * 256 + threadIdx.x;
    if (e >= NE) return;
    int row = ei[e], col = ei[NE + e];
    float a;
    if (row == col) {
        a = 1.f;
    } else {
        float4 pr = *reinterpret_cast<const float4*>(p + (size_t)row * 8);
        float4 pc = *reinterpret_cast<const float4*>(p + (size_t)col * 8 + 4);
        float4 bb = *reinterpret_cast<const float4*>(ab);
        float ev = ea[e];
        float s0 = ev / (1.f + __expf(-(pr.x + pc.x + bb.x)));
        float s1 = ev / (1.f + __expf(-(pr.y + pc.y + bb.y)));
        float s2 = ev / (1.f + __expf(-(pr.z + pc.z + bb.z)));
        float s3 = ev / (1.f + __expf(-(pr.w + pc.w + bb.w)));
        a = 0.25f * (s0 + s1 + s2 + s3);
    }
    alpha_out[e] = a;
    atomicAdd(deg + row, fabsf(a));
}

__global__ void k_dinv(const float* __restrict__ deg, float* __restrict__ dinv) {
    int n = blockIdx.x * blockDim.x + threadIdx.x;
    if (n >= NN) return;
    float d = deg[n];
    dinv[n] = (d > 0.f) ? rsqrtf(d) : 0.f;
}

// ---- CSR build: histogram -> scan -> place ----
__global__ void k_count(const int* __restrict__ ei, int* __restrict__ cnt) {
    int e = blockIdx.x * blockDim.x + threadIdx.x;
    if (e >= NE) return;
    atomicAdd(cnt + ei[e], 1);
}

__global__ __launch_bounds__(1024) void k_scan(const int* __restrict__ cnt,
                                               int* __restrict__ off,
                                               int* __restrict__ cursor) {
    __shared__ int part[1024];
    int t = threadIdx.x;
    const int CH = (NN + 1023) / 1024;  // 98
    int s = t * CH, e = s + CH; if (e > NN) e = NN; if (s > NN) s = NN;
    int sum = 0;
    for (int i = s; i < e; ++i) sum += cnt[i];
    part[t] = sum;
    __syncthreads();
    for (int o = 1; o < 1024; o <<= 1) {
        int v = (t >= o) ? part[t - o] : 0;
        __syncthreads();
        part[t] += v;
        __syncthreads();
    }
    int base = (t == 0) ? 0 : part[t - 1];
    for (int i = s; i < e; ++i) { off[i] = base; cursor[i] = base; base += cnt[i]; }
    if (t == 1023) off[NN] = part[1023];
}

// place edge into its row bucket with precomputed weight alpha*dinv[col]
__global__ __launch_bounds__(256) void k_place(const int* __restrict__ ei,
                                               const float* __restrict__ alpha,
                                               const float* __restrict__ dinv,
                                               int* __restrict__ cursor,
                                               int2* __restrict__ csr) {
    int e = blockIdx.x * 256 + threadIdx.x;
    if (e >= NE) return;
    int row = ei[e], col = ei[NE + e];
    float w = alpha[e] * dinv[col];
    int slot = atomicAdd(cursor + row, 1);
    csr[slot] = make_int2(col, __float_as_int(w));
}

// wave-per-node gather: out[n] = dinv[n] * sum_e w_e * h[col_e]   (no atomics)
__global__ __launch_bounds__(256) void k_gather(const float* __restrict__ h,
                                                const int* __restrict__ off,
                                                const int2* __restrict__ csr,
                                                const float* __restrict__ dinv,
                                                float* __restrict__ out) {
    int lane = threadIdx.x & 63;
    int n = (blockIdx.x * 256 + threadIdx.x) >> 6;
    if (n >= NN) return;
    int s = off[n], e = off[n + 1];
    float acc = 0.f;
    for (int i = s; i < e; ++i) {
        int2 cw = csr[i];  // wave-uniform 8B
        acc += __int_as_float(cw.y) * h[(size_t)cw.x * CC + lane];
    }
    out[(size_t)n * CC + lane] = dinv[n] * acc;
}

__global__ void k_idx(const int* __restrict__ ei, float* __restrict__ o) {
    int i = blockIdx.x * blockDim.x + threadIdx.x;
    if (i >= 2 * NE) return;
    o[i] = (float)ei[i];
}

extern "C" void kernel_launch(void* const* d_in, const int* in_sizes, int n_in,
                              void* d_out, int out_size, void* d_ws, size_t ws_size,
                              hipStream_t stream) {
    const float* x  = (const float*)d_in[0];
    const float* w  = (const float*)d_in[1];
    const float* aw = (const float*)d_in[2];
    const float* ab = (const float*)d_in[3];
    const float* ea = (const float*)d_in[4];
    const int*   ei = (const int*)d_in[5];
    const int*   bm = (const int*)d_in[6];
    float* out = (float*)d_out;
    float* ws  = (float*)d_ws;
    float* h     = ws + WS_H;
    float* p     = ws + WS_P;
    int*   cnt   = (int*)(ws + WS_CNT);
    int*   off   = (int*)(ws + WS_OFF);
    int*   cur   = (int*)(ws + WS_CUR);
    float* deg   = ws + WS_DEG;
    float* dinv  = ws + WS_DINV;
    float* meanb = ws + WS_MEAN;
    float* rinvb = ws + WS_RINV;
    int*   start = (int*)(ws + WS_START);
    int2*  csr   = (int2*)(ws + WS_CSR);

    hipMemsetAsync(cnt, 0, (size_t)NN * 4, stream);
    hipMemsetAsync(deg, 0, (size_t)NN * 4, stream);

    k_gemm  <<<(NN + TR - 1) / TR, 256, 0, stream>>>(x, w, h);
    k_starts<<<(NN + 256) / 256, 256, 0, stream>>>(bm, start);
    k_stats <<<NG, 256, 0, stream>>>(h, start, meanb, rinvb);
    k_norm  <<<(NN * 16 + 255) / 256, 256, 0, stream>>>(h, bm, meanb, rinvb);
    k_proj  <<<(NN * 8 + 255) / 256, 256, 0, stream>>>(h, aw, p);
    k_count <<<(NE + 255) / 256, 256, 0, stream>>>(ei, cnt);
    k_scan  <<<1, 1024, 0, stream>>>(cnt, off, cur);
    k_alpha <<<(NE + 255) / 256, 256, 0, stream>>>(p, ei, ab, ea, out + OUT_ALPHA, deg);
    k_dinv  <<<(NN + 255) / 256, 256, 0, stream>>>(deg, dinv);
    k_place <<<(NE + 255) / 256, 256, 0, stream>>>(ei, out + OUT_ALPHA, dinv, cur, csr);
    k_gather<<<25000, 256, 0, stream>>>(h, off, csr, dinv, out);
    k_idx   <<<(2 * NE + 255) / 256, 256, 0, stream>>>(ei, out + OUT_IDX);
}

// Round 9
// 735.908 us; speedup vs baseline: 1.5036x; 1.2832x over previous
//
#include <hip/hip_runtime.h>
#include <math.h>

#define NN 100000
#define NE 1600000
#define NG 64
#define CC 64
#define KK 128
#define EPSI 1e-5f
#define TR 64    // gemm row tile
#define NB 391   // (NN+255)/256 scan blocks

// ---- workspace layout (float offsets) ----
#define WS_H      0          // h[NN*64]  25.6 MB
#define WS_P      6400000    // p[NN*8]
#define WS_CNT    7200000    // int cnt[NN]
#define WS_OFF    7300000    // int off[NN+1]
#define WS_CUR    7500000    // int cursor[NN]
#define WS_DEG    7600000    // deg[NN]
#define WS_DINV   7700000    // dinv[NN]
#define WS_MEAN   7800000
#define WS_RINV   7804096
#define WS_START  7808192
#define WS_BSUM   7850000    // int bsum[NB]
#define WS_BPRE   7860000    // int bpre[NB]
#define WS_CSR    7900000    // int2 csr[NE]  12.8 MB

// ---- output layout (float offsets) ----
#define OUT_ALPHA 6400000
#define OUT_IDX   8000000

// h = x @ W  — 64x64 tile/block, 4x4 register tile/thread, xT+W in LDS.
__global__ __launch_bounds__(256) void k_gemm(const float* __restrict__ x,
                                              const float* __restrict__ w,
                                              float* __restrict__ h) {
    __shared__ float xt[KK][TR + 4];
    __shared__ float wl[KK * CC];
    int tid = threadIdx.x;
    for (int i = tid; i < KK * CC; i += 256) wl[i] = w[i];
    int base = blockIdx.x * TR;
    int nrow = NN - base; if (nrow > TR) nrow = TR;
    for (int i = tid; i < TR * KK; i += 256) {
        int r = i >> 7, k = i & (KK - 1);
        xt[k][r] = (r < nrow) ? x[(size_t)(base + r) * KK + k] : 0.f;
    }
    __syncthreads();
    int cgrp = tid & 15, rgrp = tid >> 4;
    int c0 = cgrp << 2, r0 = rgrp << 2;
    float acc[4][4];
    #pragma unroll
    for (int i = 0; i < 4; ++i)
        #pragma unroll
        for (int j = 0; j < 4; ++j) acc[i][j] = 0.f;
    #pragma unroll 8
    for (int k = 0; k < KK; ++k) {
        float4 xv = *reinterpret_cast<const float4*>(&xt[k][r0]);
        float4 wv = *reinterpret_cast<const float4*>(&wl[k * CC + c0]);
        acc[0][0] += xv.x * wv.x; acc[0][1] += xv.x * wv.y; acc[0][2] += xv.x * wv.z; acc[0][3] += xv.x * wv.w;
        acc[1][0] += xv.y * wv.x; acc[1][1] += xv.y * wv.y; acc[1][2] += xv.y * wv.z; acc[1][3] += xv.y * wv.w;
        acc[2][0] += xv.z * wv.x; acc[2][1] += xv.z * wv.y; acc[2][2] += xv.z * wv.z; acc[2][3] += xv.z * wv.w;
        acc[3][0] += xv.w * wv.x; acc[3][1] += xv.w * wv.y; acc[3][2] += xv.w * wv.z; acc[3][3] += xv.w * wv.w;
    }
    #pragma unroll
    for (int i = 0; i < 4; ++i) {
        if (r0 + i < nrow) {
            float4 o = make_float4(acc[i][0], acc[i][1], acc[i][2], acc[i][3]);
            *reinterpret_cast<float4*>(&h[(size_t)(base + r0 + i) * CC + c0]) = o;
        }
    }
}

__global__ void k_starts(const int* __restrict__ bm, int* __restrict__ start) {
    int i = blockIdx.x * blockDim.x + threadIdx.x;
    if (i > NN) return;
    if (i == 0) {
        int b = bm[0];
        for (int g = 0; g <= b; ++g) start[g] = 0;
    } else if (i == NN) {
        int b = bm[NN - 1];
        for (int g = b + 1; g <= NG; ++g) start[g] = NN;
    } else {
        int b0 = bm[i - 1], b1 = bm[i];
        for (int g = b0 + 1; g <= b1; ++g) start[g] = i;
    }
}

__global__ __launch_bounds__(256) void k_stats(const float* __restrict__ h,
                                               const int* __restrict__ start,
                                               float* __restrict__ meanb,
                                               float* __restrict__ rinvb) {
    __shared__ float ssum[4][64], ssq[4][64];
    int g = blockIdx.x;
    int s = start[g], e = start[g + 1];
    int w = threadIdx.x >> 6, lane = threadIdx.x & 63;
    float a = 0.f, b = 0.f;
    for (int r = s + w; r < e; r += 4) {
        float v = h[(size_t)r * CC + lane];
        a += v; b += v * v;
    }
    ssum[w][lane] = a; ssq[w][lane] = b;
    __syncthreads();
    if (w == 0) {
        a = ssum[0][lane] + ssum[1][lane] + ssum[2][lane] + ssum[3][lane];
        b = ssq[0][lane] + ssq[1][lane] + ssq[2][lane] + ssq[3][lane];
        float mean = 0.f, rinv = 0.f;
        if (e > s) {
            float cnt = (float)(e - s);
            mean = a / cnt;
            float var = b / cnt - mean * mean;
            rinv = rsqrtf(var + EPSI);
        }
        meanb[g * 64 + lane] = mean;
        rinvb[g * 64 + lane] = rinv;
    }
}

__global__ void k_norm(float* __restrict__ h, const int* __restrict__ bm,
                       const float* __restrict__ meanb, const float* __restrict__ rinvb) {
    int id = blockIdx.x * blockDim.x + threadIdx.x;
    if (id >= NN * 16) return;
    int i = id >> 4, c4 = (id & 15) << 2;
    int g = bm[i];
    float4 v = *reinterpret_cast<float4*>(h + (size_t)i * CC + c4);
    float4 m = *reinterpret_cast<const float4*>(meanb + g * 64 + c4);
    float4 r = *reinterpret_cast<const float4*>(rinvb + g * 64 + c4);
    v.x = (v.x - m.x) * r.x;
    v.y = (v.y - m.y) * r.y;
    v.z = (v.z - m.z) * r.z;
    v.w = (v.w - m.w) * r.w;
    *reinterpret_cast<float4*>(h + (size_t)i * CC + c4) = v;
}

__global__ __launch_bounds__(256) void k_proj(const float* __restrict__ h,
                                              const float* __restrict__ aw,
                                              float* __restrict__ p) {
    __shared__ float awl[4 * KK];
    for (int i = threadIdx.x; i < 4 * KK; i += 256) awl[i] = aw[i];
    __syncthreads();
    int id = blockIdx.x * 256 + threadIdx.x;
    int n = id >> 3, j = id & 7;
    if (n >= NN) return;
    int hd = j & 3, half = (j >> 2) * 64;
    const float* hr = h + (size_t)n * CC;
    float acc = 0.f;
    #pragma unroll
    for (int c = 0; c < CC; c += 4) {
        float4 v = *reinterpret_cast<const float4*>(hr + c);
        acc += v.x * awl[hd * KK + half + c + 0];
        acc += v.y * awl[hd * KK + half + c + 1];
        acc += v.z * awl[hd * KK + half + c + 2];
        acc += v.w * awl[hd * KK + half + c + 3];
    }
    p[(size_t)n * 8 + j] = acc;
}

__global__ __launch_bounds__(256) void k_alpha(const float* __restrict__ p,
                                               const int* __restrict__ ei,
                                               const float* __restrict__ ab,
                                               const float* __restrict__ ea,
                                               float* __restrict__ alpha_out,
                                               float* __restrict__ deg) {
    int e = blockIdx.x * 256 + threadIdx.x;
    if (e >= NE) return;
    int row = ei[e], col = ei[NE + e];
    float a;
    if (row == col) {
        a = 1.f;
    } else {
        float4 pr = *reinterpret_cast<const float4*>(p + (size_t)row * 8);
        float4 pc = *reinterpret_cast<const float4*>(p + (size_t)col * 8 + 4);
        float4 bb = *reinterpret_cast<const float4*>(ab);
        float ev = ea[e];
        float s0 = ev / (1.f + __expf(-(pr.x + pc.x + bb.x)));
        float s1 = ev / (1.f + __expf(-(pr.y + pc.y + bb.y)));
        float s2 = ev / (1.f + __expf(-(pr.z + pc.z + bb.z)));
        float s3 = ev / (1.f + __expf(-(pr.w + pc.w + bb.w)));
        a = 0.25f * (s0 + s1 + s2 + s3);
    }
    alpha_out[e] = a;
    atomicAdd(deg + row, fabsf(a));
}

__global__ void k_dinv(const float* __restrict__ deg, float* __restrict__ dinv) {
    int n = blockIdx.x * blockDim.x + threadIdx.x;
    if (n >= NN) return;
    float d = deg[n];
    dinv[n] = (d > 0.f) ? rsqrtf(d) : 0.f;
}

// ---- CSR build: histogram -> two-level scan -> place ----
__global__ void k_count(const int* __restrict__ ei, int* __restrict__ cnt) {
    int e = blockIdx.x * blockDim.x + threadIdx.x;
    if (e >= NE) return;
    atomicAdd(cnt + ei[e], 1);
}

__global__ __launch_bounds__(256) void k_blksum(const int* __restrict__ cnt,
                                                int* __restrict__ bsum) {
    __shared__ int s[256];
    int t = threadIdx.x;
    int i = blockIdx.x * 256 + t;
    s[t] = (i < NN) ? cnt[i] : 0;
    __syncthreads();
    #pragma unroll
    for (int o = 128; o > 0; o >>= 1) {
        if (t < o) s[t] += s[t + o];
        __syncthreads();
    }
    if (t == 0) bsum[blockIdx.x] = s[0];
}

__global__ __launch_bounds__(512) void k_scanb(const int* __restrict__ bsum,
                                               int* __restrict__ bpre,
                                               int* __restrict__ off) {
    __shared__ int s[512];
    int t = threadIdx.x;
    s[t] = (t < NB) ? bsum[t] : 0;
    __syncthreads();
    for (int o = 1; o < 512; o <<= 1) {
        int v = (t >= o) ? s[t - o] : 0;
        __syncthreads();
        s[t] += v;
        __syncthreads();
    }
    if (t < NB) bpre[t] = (t == 0) ? 0 : s[t - 1];
    if (t == 0) off[NN] = s[NB - 1];   // = NE
}

__global__ __launch_bounds__(256) void k_off(const int* __restrict__ cnt,
                                             const int* __restrict__ bpre,
                                             int* __restrict__ off,
                                             int* __restrict__ cursor) {
    __shared__ int s[256];
    int t = threadIdx.x;
    int i = blockIdx.x * 256 + t;
    int c = (i < NN) ? cnt[i] : 0;
    s[t] = c;
    __syncthreads();
    for (int o = 1; o < 256; o <<= 1) {
        int v = (t >= o) ? s[t - o] : 0;
        __syncthreads();
        s[t] += v;
        __syncthreads();
    }
    if (i < NN) {
        int excl = bpre[blockIdx.x] + s[t] - c;
        off[i] = excl;
        cursor[i] = excl;
    }
}

// place edge into its row bucket with precomputed weight alpha*dinv[col]
__global__ __launch_bounds__(256) void k_place(const int* __restrict__ ei,
                                               const float* __restrict__ alpha,
                                               const float* __restrict__ dinv,
                                               int* __restrict__ cursor,
                                               int2* __restrict__ csr) {
    int e = blockIdx.x * 256 + threadIdx.x;
    if (e >= NE) return;
    int row = ei[e], col = ei[NE + e];
    float w = alpha[e] * dinv[col];
    int slot = atomicAdd(cursor + row, 1);
    csr[slot] = make_int2(col, __float_as_int(w));
}

// wave-per-node gather: out[n] = dinv[n] * sum_e w_e * h[col_e]   (no atomics)
__global__ __launch_bounds__(256) void k_gather(const float* __restrict__ h,
                                                const int* __restrict__ off,
                                                const int2* __restrict__ csr,
                                                const float* __restrict__ dinv,
                                                float* __restrict__ out) {
    int lane = threadIdx.x & 63;
    int n = (blockIdx.x * 256 + threadIdx.x) >> 6;
    if (n >= NN) return;
    int s = off[n], e = off[n + 1];
    float acc = 0.f;
    for (int i = s; i < e; ++i) {
        int2 cw = csr[i];  // wave-uniform 8B
        acc += __int_as_float(cw.y) * h[(size_t)cw.x * CC + lane];
    }
    out[(size_t)n * CC + lane] = dinv[n] * acc;
}

__global__ void k_idx(const int* __restrict__ ei, float* __restrict__ o) {
    int i = blockIdx.x * blockDim.x + threadIdx.x;
    if (i >= 2 * NE) return;
    o[i] = (float)ei[i];
}

extern "C" void kernel_launch(void* const* d_in, const int* in_sizes, int n_in,
                              void* d_out, int out_size, void* d_ws, size_t ws_size,
                              hipStream_t stream) {
    const float* x  = (const float*)d_in[0];
    const float* w  = (const float*)d_in[1];
    const float* aw = (const float*)d_in[2];
    const float* ab = (const float*)d_in[3];
    const float* ea = (const float*)d_in[4];
    const int*   ei = (const int*)d_in[5];
    const int*   bm = (const int*)d_in[6];
    float* out = (float*)d_out;
    float* ws  = (float*)d_ws;
    float* h     = ws + WS_H;
    float* p     = ws + WS_P;
    int*   cnt   = (int*)(ws + WS_CNT);
    int*   off   = (int*)(ws + WS_OFF);
    int*   cur   = (int*)(ws + WS_CUR);
    float* deg   = ws + WS_DEG;
    float* dinv  = ws + WS_DINV;
    float* meanb = ws + WS_MEAN;
    float* rinvb = ws + WS_RINV;
    int*   start = (int*)(ws + WS_START);
    int*   bsum  = (int*)(ws + WS_BSUM);
    int*   bpre  = (int*)(ws + WS_BPRE);
    int2*  csr   = (int2*)(ws + WS_CSR);

    hipMemsetAsync(cnt, 0, (size_t)NN * 4, stream);
    hipMemsetAsync(deg, 0, (size_t)NN * 4, stream);

    k_gemm  <<<(NN + TR - 1) / TR, 256, 0, stream>>>(x, w, h);
    k_starts<<<(NN + 256) / 256, 256, 0, stream>>>(bm, start);
    k_stats <<<NG, 256, 0, stream>>>(h, start, meanb, rinvb);
    k_norm  <<<(NN * 16 + 255) / 256, 256, 0, stream>>>(h, bm, meanb, rinvb);
    k_proj  <<<(NN * 8 + 255) / 256, 256, 0, stream>>>(h, aw, p);
    k_count <<<(NE + 255) / 256, 256, 0, stream>>>(ei, cnt);
    k_blksum<<<NB, 256, 0, stream>>>(cnt, bsum);
    k_scanb <<<1, 512, 0, stream>>>(bsum, bpre, off);
    k_off   <<<NB, 256, 0, stream>>>(cnt, bpre, off, cur);
    k_alpha <<<(NE + 255) / 256, 256, 0, stream>>>(p, ei, ab, ea, out + OUT_ALPHA, deg);
    k_dinv  <<<(NN + 255) / 256, 256, 0, stream>>>(deg, dinv);
    k_place <<<(NE + 255) / 256, 256, 0, stream>>>(ei, out + OUT_ALPHA, dinv, cur, csr);
    k_gather<<<25000, 256, 0, stream>>>(h, off, csr, dinv, out);
    k_idx   <<<(2 * NE + 255) / 256, 256, 0, stream>>>(ei, out + OUT_IDX);
}

// Round 10
// 639.316 us; speedup vs baseline: 1.7307x; 1.1511x over previous
//
#include <hip/hip_runtime.h>
#include <math.h>

#define NN 100000
#define NE 1600000
#define NG 64
#define CC 64
#define KK 128
#define EPSI 1e-5f
#define TR 64    // gemm row tile
#define NB 391   // (NN+255)/256 scan blocks

// ---- workspace layout (float offsets) ----
#define WS_H      0          // h[NN*64] f32 (post-norm: bf16 packed in first 128B of each 256B row)
#define WS_P      6400000    // p[NN*8]
#define WS_CNT    7200000    // int cnt[NN]
#define WS_OFF    7300000    // int off[NN+1]
#define WS_CUR    7500000    // int cursor[NN]
#define WS_DEG    7600000    // deg[NN]
#define WS_DINV   7700000    // dinv[NN]
#define WS_MEAN   7800000
#define WS_RINV   7804096
#define WS_START  7808192
#define WS_BSUM   7850000    // int bsum[NB]
#define WS_BPRE   7860000    // int bpre[NB]
#define WS_CSR    7900000    // int2 csr[NE]  12.8 MB

// ---- output layout (float offsets) ----
#define OUT_ALPHA 6400000
#define OUT_IDX   8000000

__device__ __forceinline__ float bfh(unsigned short u) {
    return __uint_as_float(((unsigned)u) << 16);
}
__device__ __forceinline__ unsigned short fbf(float f) {   // RNE f32->bf16
    unsigned u = __float_as_uint(f);
    return (unsigned short)((u + 0x7FFFu + ((u >> 16) & 1u)) >> 16);
}

// h = x @ W  — 64x64 tile/block, 4x4 register tile/thread, xT+W in LDS.
__global__ __launch_bounds__(256) void k_gemm(const float* __restrict__ x,
                                              const float* __restrict__ w,
                                              float* __restrict__ h) {
    __shared__ float xt[KK][TR + 4];
    __shared__ float wl[KK * CC];
    int tid = threadIdx.x;
    for (int i = tid; i < KK * CC; i += 256) wl[i] = w[i];
    int base = blockIdx.x * TR;
    int nrow = NN - base; if (nrow > TR) nrow = TR;
    for (int i = tid; i < TR * KK; i += 256) {
        int r = i >> 7, k = i & (KK - 1);
        xt[k][r] = (r < nrow) ? x[(size_t)(base + r) * KK + k] : 0.f;
    }
    __syncthreads();
    int cgrp = tid & 15, rgrp = tid >> 4;
    int c0 = cgrp << 2, r0 = rgrp << 2;
    float acc[4][4];
    #pragma unroll
    for (int i = 0; i < 4; ++i)
        #pragma unroll
        for (int j = 0; j < 4; ++j) acc[i][j] = 0.f;
    #pragma unroll 8
    for (int k = 0; k < KK; ++k) {
        float4 xv = *reinterpret_cast<const float4*>(&xt[k][r0]);
        float4 wv = *reinterpret_cast<const float4*>(&wl[k * CC + c0]);
        acc[0][0] += xv.x * wv.x; acc[0][1] += xv.x * wv.y; acc[0][2] += xv.x * wv.z; acc[0][3] += xv.x * wv.w;
        acc[1][0] += xv.y * wv.x; acc[1][1] += xv.y * wv.y; acc[1][2] += xv.y * wv.z; acc[1][3] += xv.y * wv.w;
        acc[2][0] += xv.z * wv.x; acc[2][1] += xv.z * wv.y; acc[2][2] += xv.z * wv.z; acc[2][3] += xv.z * wv.w;
        acc[3][0] += xv.w * wv.x; acc[3][1] += xv.w * wv.y; acc[3][2] += xv.w * wv.z; acc[3][3] += xv.w * wv.w;
    }
    #pragma unroll
    for (int i = 0; i < 4; ++i) {
        if (r0 + i < nrow) {
            float4 o = make_float4(acc[i][0], acc[i][1], acc[i][2], acc[i][3]);
            *reinterpret_cast<float4*>(&h[(size_t)(base + r0 + i) * CC + c0]) = o;
        }
    }
}

__global__ void k_starts(const int* __restrict__ bm, int* __restrict__ start) {
    int i = blockIdx.x * blockDim.x + threadIdx.x;
    if (i > NN) return;
    if (i == 0) {
        int b = bm[0];
        for (int g = 0; g <= b; ++g) start[g] = 0;
    } else if (i == NN) {
        int b = bm[NN - 1];
        for (int g = b + 1; g <= NG; ++g) start[g] = NN;
    } else {
        int b0 = bm[i - 1], b1 = bm[i];
        for (int g = b0 + 1; g <= b1; ++g) start[g] = i;
    }
}

__global__ __launch_bounds__(256) void k_stats(const float* __restrict__ h,
                                               const int* __restrict__ start,
                                               float* __restrict__ meanb,
                                               float* __restrict__ rinvb) {
    __shared__ float ssum[4][64], ssq[4][64];
    int g = blockIdx.x;
    int s = start[g], e = start[g + 1];
    int w = threadIdx.x >> 6, lane = threadIdx.x & 63;
    float a = 0.f, b = 0.f;
    for (int r = s + w; r < e; r += 4) {
        float v = h[(size_t)r * CC + lane];
        a += v; b += v * v;
    }
    ssum[w][lane] = a; ssq[w][lane] = b;
    __syncthreads();
    if (w == 0) {
        a = ssum[0][lane] + ssum[1][lane] + ssum[2][lane] + ssum[3][lane];
        b = ssq[0][lane] + ssq[1][lane] + ssq[2][lane] + ssq[3][lane];
        float mean = 0.f, rinv = 0.f;
        if (e > s) {
            float cnt = (float)(e - s);
            mean = a / cnt;
            float var = b / cnt - mean * mean;
            rinv = rsqrtf(var + EPSI);
        }
        meanb[g * 64 + lane] = mean;
        rinvb[g * 64 + lane] = rinv;
    }
}

// thread-per-row: normalize and pack bf16 IN-PLACE into first 128B of the row.
// Read all 64 f32 into regs first, then write -> no intra-thread hazard; no
// cross-thread hazard (each thread owns its whole 256B row).
__global__ __launch_bounds__(256) void k_norm(float* __restrict__ h, const int* __restrict__ bm,
                                              const float* __restrict__ meanb,
                                              const float* __restrict__ rinvb) {
    int i = blockIdx.x * blockDim.x + threadIdx.x;
    if (i >= NN) return;
    int g = bm[i];
    float vals[64];
    const float4* hr = reinterpret_cast<const float4*>(h + (size_t)i * CC);
    #pragma unroll
    for (int c = 0; c < 16; ++c) {
        float4 t = hr[c];
        vals[4 * c + 0] = t.x; vals[4 * c + 1] = t.y;
        vals[4 * c + 2] = t.z; vals[4 * c + 3] = t.w;
    }
    const float* mb = meanb + g * 64;
    const float* rb = rinvb + g * 64;
    unsigned packed[32];
    #pragma unroll
    for (int j = 0; j < 32; ++j) {
        float a = (vals[2 * j]     - mb[2 * j])     * rb[2 * j];
        float b = (vals[2 * j + 1] - mb[2 * j + 1]) * rb[2 * j + 1];
        packed[j] = (unsigned)fbf(a) | ((unsigned)fbf(b) << 16);
    }
    uint4* ho = reinterpret_cast<uint4*>(reinterpret_cast<unsigned short*>(h) + (size_t)i * 128);
    #pragma unroll
    for (int q = 0; q < 8; ++q)
        ho[q] = make_uint4(packed[4 * q], packed[4 * q + 1], packed[4 * q + 2], packed[4 * q + 3]);
}

// per-node head projections from bf16 h2
__global__ __launch_bounds__(256) void k_proj(const unsigned short* __restrict__ h2,
                                              const float* __restrict__ aw,
                                              float* __restrict__ p) {
    __shared__ float awl[4 * KK];
    for (int i = threadIdx.x; i < 4 * KK; i += 256) awl[i] = aw[i];
    __syncthreads();
    int id = blockIdx.x * 256 + threadIdx.x;
    int n = id >> 3, j = id & 7;
    if (n >= NN) return;
    int hd = j & 3, half = (j >> 2) * 64;
    const unsigned short* hr = h2 + (size_t)n * 128;
    float acc = 0.f;
    #pragma unroll
    for (int c = 0; c < CC; c += 4) {
        ushort4 u = *reinterpret_cast<const ushort4*>(hr + c);
        acc += bfh(u.x) * awl[hd * KK + half + c + 0];
        acc += bfh(u.y) * awl[hd * KK + half + c + 1];
        acc += bfh(u.z) * awl[hd * KK + half + c + 2];
        acc += bfh(u.w) * awl[hd * KK + half + c + 3];
    }
    p[(size_t)n * 8 + j] = acc;
}

__global__ __launch_bounds__(256) void k_alpha(const float* __restrict__ p,
                                               const int* __restrict__ ei,
                                               const float* __restrict__ ab,
                                               const float* __restrict__ ea,
                                               float* __restrict__ alpha_out,
                                               float* __restrict__ deg) {
    int e = blockIdx.x * 256 + threadIdx.x;
    if (e >= NE) return;
    int row = ei[e], col = ei[NE + e];
    float a;
    if (row == col) {
        a = 1.f;
    } else {
        float4 pr = *reinterpret_cast<const float4*>(p + (size_t)row * 8);
        float4 pc = *reinterpret_cast<const float4*>(p + (size_t)col * 8 + 4);
        float4 bb = *reinterpret_cast<const float4*>(ab);
        float ev = ea[e];
        float s0 = ev / (1.f + __expf(-(pr.x + pc.x + bb.x)));
        float s1 = ev / (1.f + __expf(-(pr.y + pc.y + bb.y)));
        float s2 = ev / (1.f + __expf(-(pr.z + pc.z + bb.z)));
        float s3 = ev / (1.f + __expf(-(pr.w + pc.w + bb.w)));
        a = 0.25f * (s0 + s1 + s2 + s3);
    }
    alpha_out[e] = a;
    atomicAdd(deg + row, fabsf(a));
}

__global__ void k_dinv(const float* __restrict__ deg, float* __restrict__ dinv) {
    int n = blockIdx.x * blockDim.x + threadIdx.x;
    if (n >= NN) return;
    float d = deg[n];
    dinv[n] = (d > 0.f) ? rsqrtf(d) : 0.f;
}

// ---- CSR build: histogram -> two-level scan -> place ----
__global__ void k_count(const int* __restrict__ ei, int* __restrict__ cnt) {
    int e = blockIdx.x * blockDim.x + threadIdx.x;
    if (e >= NE) return;
    atomicAdd(cnt + ei[e], 1);
}

__global__ __launch_bounds__(256) void k_blksum(const int* __restrict__ cnt,
                                                int* __restrict__ bsum) {
    __shared__ int s[256];
    int t = threadIdx.x;
    int i = blockIdx.x * 256 + t;
    s[t] = (i < NN) ? cnt[i] : 0;
    __syncthreads();
    #pragma unroll
    for (int o = 128; o > 0; o >>= 1) {
        if (t < o) s[t] += s[t + o];
        __syncthreads();
    }
    if (t == 0) bsum[blockIdx.x] = s[0];
}

__global__ __launch_bounds__(512) void k_scanb(const int* __restrict__ bsum,
                                               int* __restrict__ bpre,
                                               int* __restrict__ off) {
    __shared__ int s[512];
    int t = threadIdx.x;
    s[t] = (t < NB) ? bsum[t] : 0;
    __syncthreads();
    for (int o = 1; o < 512; o <<= 1) {
        int v = (t >= o) ? s[t - o] : 0;
        __syncthreads();
        s[t] += v;
        __syncthreads();
    }
    if (t < NB) bpre[t] = (t == 0) ? 0 : s[t - 1];
    if (t == 0) off[NN] = s[NB - 1];   // = NE
}

__global__ __launch_bounds__(256) void k_off(const int* __restrict__ cnt,
                                             const int* __restrict__ bpre,
                                             int* __restrict__ off,
                                             int* __restrict__ cursor) {
    __shared__ int s[256];
    int t = threadIdx.x;
    int i = blockIdx.x * 256 + t;
    int c = (i < NN) ? cnt[i] : 0;
    s[t] = c;
    __syncthreads();
    for (int o = 1; o < 256; o <<= 1) {
        int v = (t >= o) ? s[t - o] : 0;
        __syncthreads();
        s[t] += v;
        __syncthreads();
    }
    if (i < NN) {
        int excl = bpre[blockIdx.x] + s[t] - c;
        off[i] = excl;
        cursor[i] = excl;
    }
}

__global__ __launch_bounds__(256) void k_place(const int* __restrict__ ei,
                                               const float* __restrict__ alpha,
                                               const float* __restrict__ dinv,
                                               int* __restrict__ cursor,
                                               int2* __restrict__ csr) {
    int e = blockIdx.x * 256 + threadIdx.x;
    if (e >= NE) return;
    int row = ei[e], col = ei[NE + e];
    float w = alpha[e] * dinv[col];
    int slot = atomicAdd(cursor + row, 1);
    csr[slot] = make_int2(col, __float_as_int(w));
}

// wave-per-node gather from bf16 h2, 8-wide MLP unroll (no atomics)
__global__ __launch_bounds__(256) void k_gather(const unsigned short* __restrict__ h2,
                                                const int* __restrict__ off,
                                                const int2* __restrict__ csr,
                                                const float* __restrict__ dinv,
                                                float* __restrict__ out) {
    int lane = threadIdx.x & 63;
    int n = (blockIdx.x * 256 + threadIdx.x) >> 6;
    if (n >= NN) return;
    int s = off[n], e = off[n + 1];
    float acc = 0.f;
    int i = s;
    for (; i + 8 <= e; i += 8) {
        int2 c[8];
        #pragma unroll
        for (int u = 0; u < 8; ++u) c[u] = csr[i + u];
        float v[8];
        #pragma unroll
        for (int u = 0; u < 8; ++u) v[u] = bfh(h2[(size_t)c[u].x * 128 + lane]);
        #pragma unroll
        for (int u = 0; u < 8; ++u) acc += __int_as_float(c[u].y) * v[u];
    }
    for (; i + 4 <= e; i += 4) {
        int2 c[4];
        #pragma unroll
        for (int u = 0; u < 4; ++u) c[u] = csr[i + u];
        float v[4];
        #pragma unroll
        for (int u = 0; u < 4; ++u) v[u] = bfh(h2[(size_t)c[u].x * 128 + lane]);
        #pragma unroll
        for (int u = 0; u < 4; ++u) acc += __int_as_float(c[u].y) * v[u];
    }
    for (; i < e; ++i) {
        int2 cw = csr[i];
        acc += __int_as_float(cw.y) * bfh(h2[(size_t)cw.x * 128 + lane]);
    }
    out[(size_t)n * CC + lane] = dinv[n] * acc;
}

__global__ void k_idx(const int* __restrict__ ei, float* __restrict__ o) {
    int i = blockIdx.x * blockDim.x + threadIdx.x;
    if (i >= 2 * NE) return;
    o[i] = (float)ei[i];
}

extern "C" void kernel_launch(void* const* d_in, const int* in_sizes, int n_in,
                              void* d_out, int out_size, void* d_ws, size_t ws_size,
                              hipStream_t stream) {
    const float* x  = (const float*)d_in[0];
    const float* w  = (const float*)d_in[1];
    const float* aw = (const float*)d_in[2];
    const float* ab = (const float*)d_in[3];
    const float* ea = (const float*)d_in[4];
    const int*   ei = (const int*)d_in[5];
    const int*   bm = (const int*)d_in[6];
    float* out = (float*)d_out;
    float* ws  = (float*)d_ws;
    float* h     = ws + WS_H;
    const unsigned short* h2 = (const unsigned short*)(ws + WS_H);
    float* p     = ws + WS_P;
    int*   cnt   = (int*)(ws + WS_CNT);
    int*   off   = (int*)(ws + WS_OFF);
    int*   cur   = (int*)(ws + WS_CUR);
    float* deg   = ws + WS_DEG;
    float* dinv  = ws + WS_DINV;
    float* meanb = ws + WS_MEAN;
    float* rinvb = ws + WS_RINV;
    int*   start = (int*)(ws + WS_START);
    int*   bsum  = (int*)(ws + WS_BSUM);
    int*   bpre  = (int*)(ws + WS_BPRE);
    int2*  csr   = (int2*)(ws + WS_CSR);

    hipMemsetAsync(cnt, 0, (size_t)NN * 4, stream);
    hipMemsetAsync(deg, 0, (size_t)NN * 4, stream);

    k_gemm  <<<(NN + TR - 1) / TR, 256, 0, stream>>>(x, w, h);
    k_starts<<<(NN + 256) / 256, 256, 0, stream>>>(bm, start);
    k_stats <<<NG, 256, 0, stream>>>(h, start, meanb, rinvb);
    k_norm  <<<(NN + 255) / 256, 256, 0, stream>>>(h, bm, meanb, rinvb);
    k_proj  <<<(NN * 8 + 255) / 256, 256, 0, stream>>>(h2, aw, p);
    k_count <<<(NE + 255) / 256, 256, 0, stream>>>(ei, cnt);
    k_blksum<<<NB, 256, 0, stream>>>(cnt, bsum);
    k_scanb <<<1, 512, 0, stream>>>(bsum, bpre, off);
    k_off   <<<NB, 256, 0, stream>>>(cnt, bpre, off, cur);
    k_alpha <<<(NE + 255) / 256, 256, 0, stream>>>(p, ei, ab, ea, out + OUT_ALPHA, deg);
    k_dinv  <<<(NN + 255) / 256, 256, 0, stream>>>(deg, dinv);
    k_place <<<(NE + 255) / 256, 256, 0, stream>>>(ei, out + OUT_ALPHA, dinv, cur, csr);
    k_gather<<<25000, 256, 0, stream>>>(h2, off, csr, dinv, out);
    k_idx   <<<(2 * NE + 255) / 256, 256, 0, stream>>>(ei, out + OUT_IDX);
}

// Round 13
// 518.359 us; speedup vs baseline: 2.1346x; 1.2333x over previous
//
#include <hip/hip_runtime.h>
#include <math.h>

#define NN 100000
#define NE 1600000
#define NG 64
#define CC 64
#define KK 128
#define EPSI 1e-5f
#define TR 64    // gemm row tile
#define NB 391   // (NN+255)/256 blocks

// ---- workspace layout (float offsets) ----
#define WS_H      0          // h[NN*64] f32 (post-norm: bf16 packed in first 128B of each 256B row)
#define WS_P      6400000    // p[NN*8]
#define WS_CNT    7200000    // int cnt[NN]
#define WS_OFF    7300000    // int off[NN+1]
#define WS_CUR    7500000    // int cursor[NN]
#define WS_DEG    7600000    // deg[NN]
#define WS_DINV   7700000    // dinv[NN]
#define WS_MEAN   7800000    // meanb[NG*64]
#define WS_RINV   7804096    // rinvb[NG*64]
#define WS_START  7808192    // int start[NG+1]
#define WS_SUMB   7810000    // sumb[NG*64]   (contiguous with WS_SQB for one memset)
#define WS_SQB    7814096    // sqb[NG*64]
#define WS_BSUM   7850000    // int bsum[NB]
#define WS_BPRE   7860000    // int bpre[NB]
#define WS_CSR    7900000    // unsigned csr4[NE]  6.4 MB  (col 17b | bf15(alpha) 15b)

// ---- output layout (float offsets) ----
#define OUT_ALPHA 6400000
#define OUT_IDX   8000000

__device__ __forceinline__ float bfh(unsigned short u) {
    return __uint_as_float(((unsigned)u) << 16);
}
__device__ __forceinline__ unsigned short fbf(float f) {   // RNE f32->bf16
    unsigned u = __float_as_uint(f);
    return (unsigned short)((u + 0x7FFFu + ((u >> 16) & 1u)) >> 16);
}

// h = x @ W  — 64x64 tile/block, 4x4 register tile/thread, xT+W in LDS.
__global__ __launch_bounds__(256) void k_gemm(const float* __restrict__ x,
                                              const float* __restrict__ w,
                                              float* __restrict__ h) {
    __shared__ float xt[KK][TR + 4];
    __shared__ float wl[KK * CC];
    int tid = threadIdx.x;
    for (int i = tid; i < KK * CC; i += 256) wl[i] = w[i];
    int base = blockIdx.x * TR;
    int nrow = NN - base; if (nrow > TR) nrow = TR;
    for (int i = tid; i < TR * KK; i += 256) {
        int r = i >> 7, k = i & (KK - 1);
        xt[k][r] = (r < nrow) ? x[(size_t)(base + r) * KK + k] : 0.f;
    }
    __syncthreads();
    int cgrp = tid & 15, rgrp = tid >> 4;
    int c0 = cgrp << 2, r0 = rgrp << 2;
    float acc[4][4];
    #pragma unroll
    for (int i = 0; i < 4; ++i)
        #pragma unroll
        for (int j = 0; j < 4; ++j) acc[i][j] = 0.f;
    #pragma unroll 8
    for (int k = 0; k < KK; ++k) {
        float4 xv = *reinterpret_cast<const float4*>(&xt[k][r0]);
        float4 wv = *reinterpret_cast<const float4*>(&wl[k * CC + c0]);
        acc[0][0] += xv.x * wv.x; acc[0][1] += xv.x * wv.y; acc[0][2] += xv.x * wv.z; acc[0][3] += xv.x * wv.w;
        acc[1][0] += xv.y * wv.x; acc[1][1] += xv.y * wv.y; acc[1][2] += xv.y * wv.z; acc[1][3] += xv.y * wv.w;
        acc[2][0] += xv.z * wv.x; acc[2][1] += xv.z * wv.y; acc[2][2] += xv.z * wv.z; acc[2][3] += xv.z * wv.w;
        acc[3][0] += xv.w * wv.x; acc[3][1] += xv.w * wv.y; acc[3][2] += xv.w * wv.z; acc[3][3] += xv.w * wv.w;
    }
    #pragma unroll
    for (int i = 0; i < 4; ++i) {
        if (r0 + i < nrow) {
            float4 o = make_float4(acc[i][0], acc[i][1], acc[i][2], acc[i][3]);
            *reinterpret_cast<float4*>(&h[(size_t)(base + r0 + i) * CC + c0]) = o;
        }
    }
}

__global__ void k_starts(const int* __restrict__ bm, int* __restrict__ start) {
    int i = blockIdx.x * blockDim.x + threadIdx.x;
    if (i > NN) return;
    if (i == 0) {
        int b = bm[0];
        for (int g = 0; g <= b; ++g) start[g] = 0;
    } else if (i == NN) {
        int b = bm[NN - 1];
        for (int g = b + 1; g <= NG; ++g) start[g] = NN;
    } else {
        int b0 = bm[i - 1], b1 = bm[i];
        for (int g = b0 + 1; g <= b1; ++g) start[g] = i;
    }
}

// parallel per-graph stats: wave per 64-row chunk, lane = channel,
// register accumulate with flush-on-graph-boundary (bm sorted -> rare).
__global__ __launch_bounds__(256) void k_pstats(const float* __restrict__ h,
                                                const int* __restrict__ bm,
                                                float* __restrict__ sumb,
                                                float* __restrict__ sqb) {
    int lane = threadIdx.x & 63;
    int wv = threadIdx.x >> 6;
    int rbase = blockIdx.x * 256 + wv * 64;
    if (rbase >= NN) return;
    int rend = rbase + 64; if (rend > NN) rend = NN;
    int cur_g = bm[rbase];
    float a = 0.f, b = 0.f;
    for (int r = rbase; r < rend; ++r) {
        int g = bm[r];
        if (g != cur_g) {
            atomicAdd(sumb + cur_g * 64 + lane, a);
            atomicAdd(sqb  + cur_g * 64 + lane, b);
            a = 0.f; b = 0.f; cur_g = g;
        }
        float v = h[(size_t)r * CC + lane];
        a += v; b += v * v;
    }
    atomicAdd(sumb + cur_g * 64 + lane, a);
    atomicAdd(sqb  + cur_g * 64 + lane, b);
}

__global__ void k_fstats(const float* __restrict__ sumb, const float* __restrict__ sqb,
                         const int* __restrict__ start,
                         float* __restrict__ meanb, float* __restrict__ rinvb) {
    int i = blockIdx.x * blockDim.x + threadIdx.x;   // g*64 + c
    if (i >= NG * 64) return;
    int g = i >> 6;
    int cnt = start[g + 1] - start[g];
    float mean = 0.f, rinv = 0.f;
    if (cnt > 0) {
        float fc = (float)cnt;
        mean = sumb[i] / fc;
        float var = sqb[i] / fc - mean * mean;
        rinv = rsqrtf(var + EPSI);
    }
    meanb[i] = mean;
    rinvb[i] = rinv;
}

// thread-per-row: normalize and pack bf16 IN-PLACE into first 128B of the row.
__global__ __launch_bounds__(256) void k_norm(float* __restrict__ h, const int* __restrict__ bm,
                                              const float* __restrict__ meanb,
                                              const float* __restrict__ rinvb) {
    int i = blockIdx.x * blockDim.x + threadIdx.x;
    if (i >= NN) return;
    int g = bm[i];
    float vals[64];
    const float4* hr = reinterpret_cast<const float4*>(h + (size_t)i * CC);
    #pragma unroll
    for (int c = 0; c < 16; ++c) {
        float4 t = hr[c];
        vals[4 * c + 0] = t.x; vals[4 * c + 1] = t.y;
        vals[4 * c + 2] = t.z; vals[4 * c + 3] = t.w;
    }
    const float* mb = meanb + g * 64;
    const float* rb = rinvb + g * 64;
    unsigned packed[32];
    #pragma unroll
    for (int j = 0; j < 32; ++j) {
        float a = (vals[2 * j]     - mb[2 * j])     * rb[2 * j];
        float b = (vals[2 * j + 1] - mb[2 * j + 1]) * rb[2 * j + 1];
        packed[j] = (unsigned)fbf(a) | ((unsigned)fbf(b) << 16);
    }
    uint4* ho = reinterpret_cast<uint4*>(reinterpret_cast<unsigned short*>(h) + (size_t)i * 128);
    #pragma unroll
    for (int q = 0; q < 8; ++q)
        ho[q] = make_uint4(packed[4 * q], packed[4 * q + 1], packed[4 * q + 2], packed[4 * q + 3]);
}

// per-node head projections from bf16 h2
__global__ __launch_bounds__(256) void k_proj(const unsigned short* __restrict__ h2,
                                              const float* __restrict__ aw,
                                              float* __restrict__ p) {
    __shared__ float awl[4 * KK];
    for (int i = threadIdx.x; i < 4 * KK; i += 256) awl[i] = aw[i];
    __syncthreads();
    int id = blockIdx.x * 256 + threadIdx.x;
    int n = id >> 3, j = id & 7;
    if (n >= NN) return;
    int hd = j & 3, half = (j >> 2) * 64;
    const unsigned short* hr = h2 + (size_t)n * 128;
    float acc = 0.f;
    #pragma unroll
    for (int c = 0; c < CC; c += 4) {
        ushort4 u = *reinterpret_cast<const ushort4*>(hr + c);
        acc += bfh(u.x) * awl[hd * KK + half + c + 0];
        acc += bfh(u.y) * awl[hd * KK + half + c + 1];
        acc += bfh(u.z) * awl[hd * KK + half + c + 2];
        acc += bfh(u.w) * awl[hd * KK + half + c + 3];
    }
    p[(size_t)n * 8 + j] = acc;
}

// alpha + deg + CSR placement fused (csr entry: col 17b | bf15(alpha) 15b;
// dinv[col] factor applied in k_gather)
__global__ __launch_bounds__(256) void k_alpha(const float* __restrict__ p,
                                               const int* __restrict__ ei,
                                               const float* __restrict__ ab,
                                               const float* __restrict__ ea,
                                               float* __restrict__ alpha_out,
                                               float* __restrict__ deg,
                                               int* __restrict__ cursor,
                                               unsigned* __restrict__ csr4) {
    int e = blockIdx.x * 256 + threadIdx.x;
    if (e >= NE) return;
    int row = ei[e], col = ei[NE + e];
    float a;
    if (row == col) {
        a = 1.f;
    } else {
        float4 pr = *reinterpret_cast<const float4*>(p + (size_t)row * 8);
        float4 pc = *reinterpret_cast<const float4*>(p + (size_t)col * 8 + 4);
        float4 bb = *reinterpret_cast<const float4*>(ab);
        float ev = ea[e];
        float s0 = ev / (1.f + __expf(-(pr.x + pc.x + bb.x)));
        float s1 = ev / (1.f + __expf(-(pr.y + pc.y + bb.y)));
        float s2 = ev / (1.f + __expf(-(pr.z + pc.z + bb.z)));
        float s3 = ev / (1.f + __expf(-(pr.w + pc.w + bb.w)));
        a = 0.25f * (s0 + s1 + s2 + s3);
    }
    alpha_out[e] = a;
    atomicAdd(deg + row, fabsf(a));
    int slot = atomicAdd(cursor + row, 1);
    csr4[slot] = ((unsigned)col) | (((unsigned)(fbf(a) >> 1)) << 17);
}

__global__ void k_dinv(const float* __restrict__ deg, float* __restrict__ dinv) {
    int n = blockIdx.x * blockDim.x + threadIdx.x;
    if (n >= NN) return;
    float d = deg[n];
    dinv[n] = (d > 0.f) ? rsqrtf(d) : 0.f;
}

// ---- CSR build: histogram -> two-level scan ----
__global__ void k_count(const int* __restrict__ ei, int* __restrict__ cnt) {
    int e = blockIdx.x * blockDim.x + threadIdx.x;
    if (e >= NE) return;
    atomicAdd(cnt + ei[e], 1);
}

__global__ __launch_bounds__(256) void k_blksum(const int* __restrict__ cnt,
                                                int* __restrict__ bsum) {
    __shared__ int s[256];
    int t = threadIdx.x;
    int i = blockIdx.x * 256 + t;
    s[t] = (i < NN) ? cnt[i] : 0;
    __syncthreads();
    #pragma unroll
    for (int o = 128; o > 0; o >>= 1) {
        if (t < o) s[t] += s[t + o];
        __syncthreads();
    }
    if (t == 0) bsum[blockIdx.x] = s[0];
}

__global__ __launch_bounds__(512) void k_scanb(const int* __restrict__ bsum,
                                               int* __restrict__ bpre,
                                               int* __restrict__ off) {
    __shared__ int s[512];
    int t = threadIdx.x;
    s[t] = (t < NB) ? bsum[t] : 0;
    __syncthreads();
    for (int o = 1; o < 512; o <<= 1) {
        int v = (t >= o) ? s[t - o] : 0;
        __syncthreads();
        s[t] += v;
        __syncthreads();
    }
    if (t < NB) bpre[t] = (t == 0) ? 0 : s[t - 1];
    if (t == 0) off[NN] = s[NB - 1];   // = NE
}

__global__ __launch_bounds__(256) void k_off(const int* __restrict__ cnt,
                                             const int* __restrict__ bpre,
                                             int* __restrict__ off,
                                             int* __restrict__ cursor) {
    __shared__ int s[256];
    int t = threadIdx.x;
    int i = blockIdx.x * 256 + t;
    int c = (i < NN) ? cnt[i] : 0;
    s[t] = c;
    __syncthreads();
    for (int o = 1; o < 256; o <<= 1) {
        int v = (t >= o) ? s[t - o] : 0;
        __syncthreads();
        s[t] += v;
        __syncthreads();
    }
    if (i < NN) {
        int excl = bpre[blockIdx.x] + s[t] - c;
        off[i] = excl;
        cursor[i] = excl;
    }
}

// wave-per-node gather from bf16 h2, 8-wide MLP unroll (no atomics)
__global__ __launch_bounds__(256) void k_gather(const unsigned short* __restrict__ h2,
                                                const int* __restrict__ off,
                                                const unsigned* __restrict__ csr4,
                                                const float* __restrict__ dinv,
                                                float* __restrict__ out) {
    int lane = threadIdx.x & 63;
    int n = (blockIdx.x * 256 + threadIdx.x) >> 6;
    if (n >= NN) return;
    int s = off[n], e = off[n + 1];
    float acc = 0.f;
    int i = s;
    for (; i + 8 <= e; i += 8) {
        unsigned c[8];
        #pragma unroll
        for (int u = 0; u < 8; ++u) c[u] = csr4[i + u];
        float wv[8], hv[8];
        #pragma unroll
        for (int u = 0; u < 8; ++u) {
            int cl = c[u] & 0x1FFFF;
            wv[u] = dinv[cl] * bfh((unsigned short)((c[u] >> 17) << 1));
            hv[u] = bfh(h2[(size_t)cl * 128 + lane]);
        }
        #pragma unroll
        for (int u = 0; u < 8; ++u) acc += wv[u] * hv[u];
    }
    for (; i + 4 <= e; i += 4) {
        unsigned c[4];
        #pragma unroll
        for (int u = 0; u < 4; ++u) c[u] = csr4[i + u];
        float wv[4], hv[4];
        #pragma unroll
        for (int u = 0; u < 4; ++u) {
            int cl = c[u] & 0x1FFFF;
            wv[u] = dinv[cl] * bfh((unsigned short)((c[u] >> 17) << 1));
            hv[u] = bfh(h2[(size_t)cl * 128 + lane]);
        }
        #pragma unroll
        for (int u = 0; u < 4; ++u) acc += wv[u] * hv[u];
    }
    for (; i < e; ++i) {
        unsigned cw = csr4[i];
        int cl = cw & 0x1FFFF;
        acc += dinv[cl] * bfh((unsigned short)((cw >> 17) << 1)) * bfh(h2[(size_t)cl * 128 + lane]);
    }
    out[(size_t)n * CC + lane] = dinv[n] * acc;
}

__global__ void k_idx(const int* __restrict__ ei, float* __restrict__ o) {
    int i = blockIdx.x * blockDim.x + threadIdx.x;
    if (i >= 2 * NE) return;
    o[i] = (float)ei[i];
}

extern "C" void kernel_launch(void* const* d_in, const int* in_sizes, int n_in,
                              void* d_out, int out_size, void* d_ws, size_t ws_size,
                              hipStream_t stream) {
    const float* x  = (const float*)d_in[0];
    const float* w  = (const float*)d_in[1];
    const float* aw = (const float*)d_in[2];
    const float* ab = (const float*)d_in[3];
    const float* ea = (const float*)d_in[4];
    const int*   ei = (const int*)d_in[5];
    const int*   bm = (const int*)d_in[6];
    float* out = (float*)d_out;
    float* ws  = (float*)d_ws;
    float* h     = ws + WS_H;
    const unsigned short* h2 = (const unsigned short*)(ws + WS_H);
    float* p     = ws + WS_P;
    int*   cnt   = (int*)(ws + WS_CNT);
    int*   off   = (int*)(ws + WS_OFF);
    int*   cur   = (int*)(ws + WS_CUR);
    float* deg   = ws + WS_DEG;
    float* dinv  = ws + WS_DINV;
    float* meanb = ws + WS_MEAN;
    float* rinvb = ws + WS_RINV;
    int*   start = (int*)(ws + WS_START);
    float* sumb  = ws + WS_SUMB;
    float* sqb   = ws + WS_SQB;
    int*   bsum  = (int*)(ws + WS_BSUM);
    int*   bpre  = (int*)(ws + WS_BPRE);
    unsigned* csr4 = (unsigned*)(ws + WS_CSR);

    hipMemsetAsync(cnt, 0, (size_t)NN * 4, stream);
    hipMemsetAsync(deg, 0, (size_t)NN * 4, stream);
    hipMemsetAsync(sumb, 0, (size_t)2 * NG * 64 * 4, stream);  // sumb+sqb contiguous

    k_gemm  <<<(NN + TR - 1) / TR, 256, 0, stream>>>(x, w, h);
    k_starts<<<(NN + 256) / 256, 256, 0, stream>>>(bm, start);
    k_pstats<<<NB, 256, 0, stream>>>(h, bm, sumb, sqb);
    k_fstats<<<16, 256, 0, stream>>>(sumb, sqb, start, meanb, rinvb);
    k_norm  <<<(NN + 255) / 256, 256, 0, stream>>>(h, bm, meanb, rinvb);
    k_proj  <<<(NN * 8 + 255) / 256, 256, 0, stream>>>(h2, aw, p);
    k_count <<<(NE + 255) / 256, 256, 0, stream>>>(ei, cnt);
    k_blksum<<<NB, 256, 0, stream>>>(cnt, bsum);
    k_scanb <<<1, 512, 0, stream>>>(bsum, bpre, off);
    k_off   <<<NB, 256, 0, stream>>>(cnt, bpre, off, cur);
    k_alpha <<<(NE + 255) / 256, 256, 0, stream>>>(p, ei, ab, ea, out + OUT_ALPHA, deg, cur, csr4);
    k_dinv  <<<(NN + 255) / 256, 256, 0, stream>>>(deg, dinv);
    k_gather<<<25000, 256, 0, stream>>>(h2, off, csr4, dinv, out);
    k_idx   <<<(2 * NE + 255) / 256, 256, 0, stream>>>(ei, out + OUT_IDX);
}

// Round 15
// 451.872 us; speedup vs baseline: 2.4487x; 1.1471x over previous
//
#include <hip/hip_runtime.h>
#include <math.h>

#define NN 100000
#define NE 1600000
#define NG 64
#define CC 64
#define KK 128
#define EPSI 1e-5f
#define TR 64    // gemm row tile
#define NB 391   // (NN+255)/256 blocks

// ---- workspace layout (float offsets) ----
#define WS_H      0          // h[NN*64] f32 (post-norm: bf16 packed in first 128B of each 256B row)
#define WS_P      6400000    // p[NN*8]
#define WS_CNT    7200000    // int cnt[NN]
#define WS_OFF    7300000    // int off[NN+1]
#define WS_DEGC   7500000    // u64 degcnt[NN]  (slot:22b<<42 | sum|alpha|*2^24:42b)  800KB
#define WS_DINV   7700000    // dinv[NN]
#define WS_MEAN   7800000    // meanb[NG*64]
#define WS_RINV   7804096    // rinvb[NG*64]
#define WS_START  7808192    // int start[NG+1]
#define WS_SUMB   7810000    // sumb[NG*64]   (contiguous with WS_SQB for one memset)
#define WS_SQB    7814096    // sqb[NG*64]
#define WS_BSUM   7850000    // int bsum[NB]
#define WS_BPRE   7860000    // int bpre[NB]
#define WS_CSR    7900000    // unsigned csr4[NE]  6.4 MB  (col 17b | bf15(alpha) 15b)

// ---- output layout (float offsets) ----
#define OUT_ALPHA 6400000
#define OUT_IDX   8000000

__device__ __forceinline__ float bfh(unsigned short u) {
    return __uint_as_float(((unsigned)u) << 16);
}
__device__ __forceinline__ unsigned short fbf(float f) {   // RNE f32->bf16
    unsigned u = __float_as_uint(f);
    return (unsigned short)((u + 0x7FFFu + ((u >> 16) & 1u)) >> 16);
}

// h = x @ W  — 64x64 tile/block, 4x4 register tile/thread, xT+W in LDS.
__global__ __launch_bounds__(256) void k_gemm(const float* __restrict__ x,
                                              const float* __restrict__ w,
                                              float* __restrict__ h) {
    __shared__ float xt[KK][TR + 4];
    __shared__ float wl[KK * CC];
    int tid = threadIdx.x;
    for (int i = tid; i < KK * CC; i += 256) wl[i] = w[i];
    int base = blockIdx.x * TR;
    int nrow = NN - base; if (nrow > TR) nrow = TR;
    for (int i = tid; i < TR * KK; i += 256) {
        int r = i >> 7, k = i & (KK - 1);
        xt[k][r] = (r < nrow) ? x[(size_t)(base + r) * KK + k] : 0.f;
    }
    __syncthreads();
    int cgrp = tid & 15, rgrp = tid >> 4;
    int c0 = cgrp << 2, r0 = rgrp << 2;
    float acc[4][4];
    #pragma unroll
    for (int i = 0; i < 4; ++i)
        #pragma unroll
        for (int j = 0; j < 4; ++j) acc[i][j] = 0.f;
    #pragma unroll 8
    for (int k = 0; k < KK; ++k) {
        float4 xv = *reinterpret_cast<const float4*>(&xt[k][r0]);
        float4 wv = *reinterpret_cast<const float4*>(&wl[k * CC + c0]);
        acc[0][0] += xv.x * wv.x; acc[0][1] += xv.x * wv.y; acc[0][2] += xv.x * wv.z; acc[0][3] += xv.x * wv.w;
        acc[1][0] += xv.y * wv.x; acc[1][1] += xv.y * wv.y; acc[1][2] += xv.y * wv.z; acc[1][3] += xv.y * wv.w;
        acc[2][0] += xv.z * wv.x; acc[2][1] += xv.z * wv.y; acc[2][2] += xv.z * wv.z; acc[2][3] += xv.z * wv.w;
        acc[3][0] += xv.w * wv.x; acc[3][1] += xv.w * wv.y; acc[3][2] += xv.w * wv.z; acc[3][3] += xv.w * wv.w;
    }
    #pragma unroll
    for (int i = 0; i < 4; ++i) {
        if (r0 + i < nrow) {
            float4 o = make_float4(acc[i][0], acc[i][1], acc[i][2], acc[i][3]);
            *reinterpret_cast<float4*>(&h[(size_t)(base + r0 + i) * CC + c0]) = o;
        }
    }
}

__global__ void k_starts(const int* __restrict__ bm, int* __restrict__ start) {
    int i = blockIdx.x * blockDim.x + threadIdx.x;
    if (i > NN) return;
    if (i == 0) {
        int b = bm[0];
        for (int g = 0; g <= b; ++g) start[g] = 0;
    } else if (i == NN) {
        int b = bm[NN - 1];
        for (int g = b + 1; g <= NG; ++g) start[g] = NN;
    } else {
        int b0 = bm[i - 1], b1 = bm[i];
        for (int g = b0 + 1; g <= b1; ++g) start[g] = i;
    }
}

// parallel per-graph stats: wave per 64-row chunk, lane = channel,
// register accumulate with flush-on-graph-boundary (bm sorted -> rare).
__global__ __launch_bounds__(256) void k_pstats(const float* __restrict__ h,
                                                const int* __restrict__ bm,
                                                float* __restrict__ sumb,
                                                float* __restrict__ sqb) {
    int lane = threadIdx.x & 63;
    int wv = threadIdx.x >> 6;
    int rbase = blockIdx.x * 256 + wv * 64;
    if (rbase >= NN) return;
    int rend = rbase + 64; if (rend > NN) rend = NN;
    int cur_g = bm[rbase];
    float a = 0.f, b = 0.f;
    for (int r = rbase; r < rend; ++r) {
        int g = bm[r];
        if (g != cur_g) {
            atomicAdd(sumb + cur_g * 64 + lane, a);
            atomicAdd(sqb  + cur_g * 64 + lane, b);
            a = 0.f; b = 0.f; cur_g = g;
        }
        float v = h[(size_t)r * CC + lane];
        a += v; b += v * v;
    }
    atomicAdd(sumb + cur_g * 64 + lane, a);
    atomicAdd(sqb  + cur_g * 64 + lane, b);
}

__global__ void k_fstats(const float* __restrict__ sumb, const float* __restrict__ sqb,
                         const int* __restrict__ start,
                         float* __restrict__ meanb, float* __restrict__ rinvb) {
    int i = blockIdx.x * blockDim.x + threadIdx.x;   // g*64 + c
    if (i >= NG * 64) return;
    int g = i >> 6;
    int cnt = start[g + 1] - start[g];
    float mean = 0.f, rinv = 0.f;
    if (cnt > 0) {
        float fc = (float)cnt;
        mean = sumb[i] / fc;
        float var = sqb[i] / fc - mean * mean;
        rinv = rsqrtf(var + EPSI);
    }
    meanb[i] = mean;
    rinvb[i] = rinv;
}

// thread-per-row: normalize and pack bf16 IN-PLACE into first 128B of the row.
__global__ __launch_bounds__(256) void k_norm(float* __restrict__ h, const int* __restrict__ bm,
                                              const float* __restrict__ meanb,
                                              const float* __restrict__ rinvb) {
    int i = blockIdx.x * blockDim.x + threadIdx.x;
    if (i >= NN) return;
    int g = bm[i];
    float vals[64];
    const float4* hr = reinterpret_cast<const float4*>(h + (size_t)i * CC);
    #pragma unroll
    for (int c = 0; c < 16; ++c) {
        float4 t = hr[c];
        vals[4 * c + 0] = t.x; vals[4 * c + 1] = t.y;
        vals[4 * c + 2] = t.z; vals[4 * c + 3] = t.w;
    }
    const float* mb = meanb + g * 64;
    const float* rb = rinvb + g * 64;
    unsigned packed[32];
    #pragma unroll
    for (int j = 0; j < 32; ++j) {
        float a = (vals[2 * j]     - mb[2 * j])     * rb[2 * j];
        float b = (vals[2 * j + 1] - mb[2 * j + 1]) * rb[2 * j + 1];
        packed[j] = (unsigned)fbf(a) | ((unsigned)fbf(b) << 16);
    }
    uint4* ho = reinterpret_cast<uint4*>(reinterpret_cast<unsigned short*>(h) + (size_t)i * 128);
    #pragma unroll
    for (int q = 0; q < 8; ++q)
        ho[q] = make_uint4(packed[4 * q], packed[4 * q + 1], packed[4 * q + 2], packed[4 * q + 3]);
}

// per-node head projections from bf16 h2
__global__ __launch_bounds__(256) void k_proj(const unsigned short* __restrict__ h2,
                                              const float* __restrict__ aw,
                                              float* __restrict__ p) {
    __shared__ float awl[4 * KK];
    for (int i = threadIdx.x; i < 4 * KK; i += 256) awl[i] = aw[i];
    __syncthreads();
    int id = blockIdx.x * 256 + threadIdx.x;
    int n = id >> 3, j = id & 7;
    if (n >= NN) return;
    int hd = j & 3, half = (j >> 2) * 64;
    const unsigned short* hr = h2 + (size_t)n * 128;
    float acc = 0.f;
    #pragma unroll
    for (int c = 0; c < CC; c += 4) {
        ushort4 u = *reinterpret_cast<const ushort4*>(hr + c);
        acc += bfh(u.x) * awl[hd * KK + half + c + 0];
        acc += bfh(u.y) * awl[hd * KK + half + c + 1];
        acc += bfh(u.z) * awl[hd * KK + half + c + 2];
        acc += bfh(u.w) * awl[hd * KK + half + c + 3];
    }
    p[(size_t)n * 8 + j] = acc;
}

// alpha + fused deg/slot atomic + nt CSR store.
// degcnt[row]: (slot:22b << 42) | fixed-point(sum |alpha| * 2^24):42b.
// Seeded by k_off with off[row]<<42, so returned high bits ARE the slot.
__global__ __launch_bounds__(256) void k_alpha(const float* __restrict__ p,
                                               const int* __restrict__ ei,
                                               const float* __restrict__ ab,
                                               const float* __restrict__ ea,
                                               float* __restrict__ alpha_out,
                                               unsigned long long* __restrict__ degcnt,
                                               unsigned* __restrict__ csr4) {
    int e = blockIdx.x * 256 + threadIdx.x;
    if (e >= NE) return;
    int row = ei[e], col = ei[NE + e];
    float a;
    if (row == col) {
        a = 1.f;
    } else {
        float4 pr = *reinterpret_cast<const float4*>(p + (size_t)row * 8);
        float4 pc = *reinterpret_cast<const float4*>(p + (size_t)col * 8 + 4);
        float4 bb = *reinterpret_cast<const float4*>(ab);
        float ev = ea[e];
        float s0 = ev / (1.f + __expf(-(pr.x + pc.x + bb.x)));
        float s1 = ev / (1.f + __expf(-(pr.y + pc.y + bb.y)));
        float s2 = ev / (1.f + __expf(-(pr.z + pc.z + bb.z)));
        float s3 = ev / (1.f + __expf(-(pr.w + pc.w + bb.w)));
        a = 0.25f * (s0 + s1 + s2 + s3);
    }
    alpha_out[e] = a;
    unsigned long long pk = (1ULL << 42) | (unsigned long long)(fabsf(a) * 16777216.0f);
    unsigned long long old = atomicAdd(degcnt + row, pk);
    int slot = (int)(old >> 42);
    unsigned entry = ((unsigned)col) | (((unsigned)(fbf(a) >> 1)) << 17);
    __builtin_nontemporal_store(entry, csr4 + slot);
}

__global__ void k_dinv(const unsigned long long* __restrict__ degcnt,
                       float* __restrict__ dinv) {
    int n = blockIdx.x * blockDim.x + threadIdx.x;
    if (n >= NN) return;
    unsigned long long v = degcnt[n];
    float d = (float)(v & ((1ULL << 42) - 1)) * (1.0f / 16777216.0f);
    dinv[n] = (d > 0.f) ? rsqrtf(d) : 0.f;
}

// ---- CSR build: histogram -> two-level scan ----
__global__ void k_count(const int* __restrict__ ei, int* __restrict__ cnt) {
    int e = blockIdx.x * blockDim.x + threadIdx.x;
    if (e >= NE) return;
    atomicAdd(cnt + ei[e], 1);
}

__global__ __launch_bounds__(256) void k_blksum(const int* __restrict__ cnt,
                                                int* __restrict__ bsum) {
    __shared__ int s[256];
    int t = threadIdx.x;
    int i = blockIdx.x * 256 + t;
    s[t] = (i < NN) ? cnt[i] : 0;
    __syncthreads();
    #pragma unroll
    for (int o = 128; o > 0; o >>= 1) {
        if (t < o) s[t] += s[t + o];
        __syncthreads();
    }
    if (t == 0) bsum[blockIdx.x] = s[0];
}

__global__ __launch_bounds__(512) void k_scanb(const int* __restrict__ bsum,
                                               int* __restrict__ bpre,
                                               int* __restrict__ off) {
    __shared__ int s[512];
    int t = threadIdx.x;
    s[t] = (t < NB) ? bsum[t] : 0;
    __syncthreads();
    for (int o = 1; o < 512; o <<= 1) {
        int v = (t >= o) ? s[t - o] : 0;
        __syncthreads();
        s[t] += v;
        __syncthreads();
    }
    if (t < NB) bpre[t] = (t == 0) ? 0 : s[t - 1];
    if (t == 0) off[NN] = s[NB - 1];   // = NE
}

// in-block scan -> off[i]; also seeds degcnt[i] = off[i]<<42 for k_alpha
__global__ __launch_bounds__(256) void k_off(const int* __restrict__ cnt,
                                             const int* __restrict__ bpre,
                                             int* __restrict__ off,
                                             unsigned long long* __restrict__ degcnt) {
    __shared__ int s[256];
    int t = threadIdx.x;
    int i = blockIdx.x * 256 + t;
    int c = (i < NN) ? cnt[i] : 0;
    s[t] = c;
    __syncthreads();
    for (int o = 1; o < 256; o <<= 1) {
        int v = (t >= o) ? s[t - o] : 0;
        __syncthreads();
        s[t] += v;
        __syncthreads();
    }
    if (i < NN) {
        int excl = bpre[blockIdx.x] + s[t] - c;
        off[i] = excl;
        degcnt[i] = (unsigned long long)excl << 42;
    }
}

// wave-per-node gather from bf16 h2, 8-wide MLP unroll (no atomics)
__global__ __launch_bounds__(256) void k_gather(const unsigned short* __restrict__ h2,
                                                const int* __restrict__ off,
                                                const unsigned* __restrict__ csr4,
                                                const float* __restrict__ dinv,
                                                float* __restrict__ out) {
    int lane = threadIdx.x & 63;
    int n = (blockIdx.x * 256 + threadIdx.x) >> 6;
    if (n >= NN) return;
    int s = off[n], e = off[n + 1];
    float acc = 0.f;
    int i = s;
    for (; i + 8 <= e; i += 8) {
        unsigned c[8];
        #pragma unroll
        for (int u = 0; u < 8; ++u) c[u] = csr4[i + u];
        float wv[8], hv[8];
        #pragma unroll
        for (int u = 0; u < 8; ++u) {
            int cl = c[u] & 0x1FFFF;
            wv[u] = dinv[cl] * bfh((unsigned short)((c[u] >> 17) << 1));
            hv[u] = bfh(h2[(size_t)cl * 128 + lane]);
        }
        #pragma unroll
        for (int u = 0; u < 8; ++u) acc += wv[u] * hv[u];
    }
    for (; i + 4 <= e; i += 4) {
        unsigned c[4];
        #pragma unroll
        for (int u = 0; u < 4; ++u) c[u] = csr4[i + u];
        float wv[4], hv[4];
        #pragma unroll
        for (int u = 0; u < 4; ++u) {
            int cl = c[u] & 0x1FFFF;
            wv[u] = dinv[cl] * bfh((unsigned short)((c[u] >> 17) << 1));
            hv[u] = bfh(h2[(size_t)cl * 128 + lane]);
        }
        #pragma unroll
        for (int u = 0; u < 4; ++u) acc += wv[u] * hv[u];
    }
    for (; i < e; ++i) {
        unsigned cw = csr4[i];
        int cl = cw & 0x1FFFF;
        acc += dinv[cl] * bfh((unsigned short)((cw >> 17) << 1)) * bfh(h2[(size_t)cl * 128 + lane]);
    }
    out[(size_t)n * CC + lane] = dinv[n] * acc;
}

__global__ void k_idx(const int* __restrict__ ei, float* __restrict__ o) {
    int i = blockIdx.x * blockDim.x + threadIdx.x;
    if (i >= 2 * NE) return;
    o[i] = (float)ei[i];
}

extern "C" void kernel_launch(void* const* d_in, const int* in_sizes, int n_in,
                              void* d_out, int out_size, void* d_ws, size_t ws_size,
                              hipStream_t stream) {
    const float* x  = (const float*)d_in[0];
    const float* w  = (const float*)d_in[1];
    const float* aw = (const float*)d_in[2];
    const float* ab = (const float*)d_in[3];
    const float* ea = (const float*)d_in[4];
    const int*   ei = (const int*)d_in[5];
    const int*   bm = (const int*)d_in[6];
    float* out = (float*)d_out;
    float* ws  = (float*)d_ws;
    float* h     = ws + WS_H;
    const unsigned short* h2 = (const unsigned short*)(ws + WS_H);
    float* p     = ws + WS_P;
    int*   cnt   = (int*)(ws + WS_CNT);
    int*   off   = (int*)(ws + WS_OFF);
    unsigned long long* degcnt = (unsigned long long*)(ws + WS_DEGC);
    float* dinv  = ws + WS_DINV;
    float* meanb = ws + WS_MEAN;
    float* rinvb = ws + WS_RINV;
    int*   start = (int*)(ws + WS_START);
    float* sumb  = ws + WS_SUMB;
    float* sqb   = ws + WS_SQB;
    int*   bsum  = (int*)(ws + WS_BSUM);
    int*   bpre  = (int*)(ws + WS_BPRE);
    unsigned* csr4 = (unsigned*)(ws + WS_CSR);

    hipMemsetAsync(cnt, 0, (size_t)NN * 4, stream);
    hipMemsetAsync(sumb, 0, (size_t)2 * NG * 64 * 4, stream);  // sumb+sqb contiguous

    k_gemm  <<<(NN + TR - 1) / TR, 256, 0, stream>>>(x, w, h);
    k_starts<<<(NN + 256) / 256, 256, 0, stream>>>(bm, start);
    k_pstats<<<NB, 256, 0, stream>>>(h, bm, sumb, sqb);
    k_fstats<<<16, 256, 0, stream>>>(sumb, sqb, start, meanb, rinvb);
    k_norm  <<<(NN + 255) / 256, 256, 0, stream>>>(h, bm, meanb, rinvb);
    k_proj  <<<(NN * 8 + 255) / 256, 256, 0, stream>>>(h2, aw, p);
    k_count <<<(NE + 255) / 256, 256, 0, stream>>>(ei, cnt);
    k_blksum<<<NB, 256, 0, stream>>>(cnt, bsum);
    k_scanb <<<1, 512, 0, stream>>>(bsum, bpre, off);
    k_off   <<<NB, 256, 0, stream>>>(cnt, bpre, off, degcnt);
    k_alpha <<<(NE + 255) / 256, 256, 0, stream>>>(p, ei, ab, ea, out + OUT_ALPHA, degcnt, csr4);
    k_dinv  <<<(NN + 255) / 256, 256, 0, stream>>>(degcnt, dinv);
    k_gather<<<25000, 256, 0, stream>>>(h2, off, csr4, dinv, out);
    k_idx   <<<(2 * NE + 255) / 256, 256, 0, stream>>>(ei, out + OUT_IDX);
}